// Round 5
// baseline (43.242 us; speedup 1.0000x reference)
//
#include <hip/hip_runtime.h>

typedef float2 cpx;

__device__ __forceinline__ cpx cmul(cpx a, cpx b){
  return make_float2(a.x*b.x - a.y*b.y, a.x*b.y + a.y*b.x);
}
__device__ __forceinline__ cpx cadd(cpx a, cpx b){ return make_float2(a.x+b.x, a.y+b.y); }
__device__ __forceinline__ cpx czero(){ return make_float2(0.f,0.f); }

// p: 1=X -> RY(-90)=[[C,C],[-C,C]], 2=Y -> RX(+90)=[[C,-iC],[-iC,C]], 3=Z -> I
__device__ __forceinline__ cpx basis_e(int p, int i, int j){
  const float C = 0.70710678f;
  if (p==1){ float s = (i==1 && j==0) ? -C : C; return make_float2(s, 0.f); }
  else if (p==2){ if (i==j) return make_float2(C,0.f); return make_float2(0.f,-C); }
  else { return make_float2(i==j ? 1.f : 0.f, 0.f); }
}

// 1=RX, 2=RY, 3=RZ (half-angle ch, sh)
__device__ __forceinline__ cpx rot_e(int p, int i, int j, float ch, float sh){
  if (p==1){ if (i==j) return make_float2(ch,0.f); return make_float2(0.f,-sh); }
  else if (p==2){ if (i==j) return make_float2(ch,0.f); return make_float2(i==1?sh:-sh, 0.f); }
  else { if (i!=j) return czero(); return make_float2(ch, i==0?-sh:sh); }
}

// Entry (r,c) of gate i (1..15), closed form. pa=i>>2, pb=i&3 (0=I,1=X,2=Y,3=Z).
__device__ __forceinline__ cpx gate_entry(int i, int r, int c, float ch, float sh){
  int pa = i>>2, pb = i&3;
  if (pa==0 || pb==0){
    int p = pa ? pa : pb;
    if (pa) return ((r&1)==(c&1))   ? rot_e(p, r>>1, c>>1, ch, sh) : czero();
    else    return ((r>>1)==(c>>1)) ? rot_e(p, r&1,  c&1,  ch, sh) : czero();
  } else {
    // G = P * diag(em,ep,ep,em) * P, P = kron(BA,BB) (faithful: same P both sides)
    cpx em = make_float2(ch,-sh), ep = make_float2(ch,sh);
    cpx s = czero();
    for (int m=0;m<4;m++){
      cpx Prm = cmul(basis_e(pa, r>>1, m>>1), basis_e(pb, r&1, m&1));
      cpx Pmc = cmul(basis_e(pa, m>>1, c>>1), basis_e(pb, m&1, c&1));
      cpx d = (m==0 || m==3) ? em : ep;
      s = cadd(s, cmul(cmul(Prm, d), Pmc));
    }
    return s;
  }
}

// MPS bond-2 form: psi(b19..b0) = s(b19)^T * T^{b18} * ... * T^{b2} * e(b1,b0),
//   T^z[yi][yo] = U[(z<<1)|yo, yi<<1],  s(b)=row0 of T^b,  e(b1,b0)_y = U[(b1<<1)|b0, y<<1].
// Tables: u4[b19..b16] = s^T T T T (row-vec), M4[p3..p0] = T T T T (2x2),
//         f4[b3..b0] = T^{b3} T^{b2} e(b1,b0) (col-vec).
// out(i) = | u4[i>>16] * M4[(i>>12)&15] * M4[(i>>8)&15] * M4[(i>>4)&15] * f4[i&15] |^2
// 5 dependent phases: P-pairs -> Q -> R -> tables -> combine+store.
__global__ __launch_bounds__(256) void mps_fused(const float* __restrict__ params,
                                                 float* __restrict__ out){
  __shared__ __align__(16) cpx P[8][16];   // pair products (P[7]=G15)
  __shared__ __align__(16) cpx Q[4][16];
  __shared__ __align__(16) cpx R[2][16];   // U = R[1]*R[0]
  __shared__ __align__(16) cpx u4[16][2];
  __shared__ __align__(16) cpx M4[16][4];  // [0]=M00 [1]=M01 [2]=M10 [3]=M11
  __shared__ __align__(16) cpx f4[16][2];
  const int t = threadIdx.x;

  // ---- Phase 1: P[p] = G_{2p+2} * G_{2p+1} (p<7), P[7]=G15; entries from closed form ----
  if (t < 128){
    int p = t>>4, e = t&15, r = e>>2, c = e&3;
    if (p < 7){
      int ga = 2*p+2, gb = 2*p+1;
      float ha = 0.5f*params[ga-1], hb = 0.5f*params[gb-1];
      float cha = cosf(ha), sha = sinf(ha);
      float chb = cosf(hb), shb = sinf(hb);
      cpx s = czero();
      for (int k=0;k<4;k++)
        s = cadd(s, cmul(gate_entry(ga, r, k, cha, sha), gate_entry(gb, k, c, chb, shb)));
      P[p][e] = s;
    } else {
      float h = 0.5f*params[14];
      P[7][e] = gate_entry(15, r, c, cosf(h), sinf(h));
    }
  }
  __syncthreads();

  // ---- Phase 2: Q[p] = P[2p+1]*P[2p] ----
  if (t < 64){
    int p = t>>4, e = t&15, r = e>>2, c = e&3;
    cpx s = czero();
    for (int k=0;k<4;k++) s = cadd(s, cmul(P[2*p+1][r*4+k], P[2*p][k*4+c]));
    Q[p][e] = s;
  }
  __syncthreads();

  // ---- Phase 3: R[p] = Q[2p+1]*Q[2p] ----
  if (t < 32){
    int p = t>>4, e = t&15, r = e>>2, c = e&3;
    cpx s = czero();
    for (int k=0;k<4;k++) s = cadd(s, cmul(Q[2*p+1][r*4+k], Q[2*p][k*4+c]));
    R[p][e] = s;
  }
  __syncthreads();

  // ---- Phase 4: tables (U entries formed on the fly: Uent(a,b)=sum_k R1[a,k]*R0[k,b]) ----
  if (t < 48){
    int kind = t>>4, pat = t&15;
    cpx T[2][2][2];  // [z][yi][yo]
    for (int z=0;z<2;z++) for (int yi=0; yi<2; yi++) for (int yo=0; yo<2; yo++){
      int a = (z<<1)|yo, b = yi<<1;
      cpx s = czero();
      for (int k=0;k<4;k++) s = cadd(s, cmul(R[1][a*4+k], R[0][k*4+b]));
      T[z][yi][yo] = s;
    }
    if (kind == 0){
      int b19=pat>>3, b18=(pat>>2)&1, b17=(pat>>1)&1, b16=pat&1;
      cpx r0 = T[b19][0][0], r1 = T[b19][0][1];   // s(b19) = row 0 of T^{b19}
      int bs[3] = {b18, b17, b16};
      for (int q=0;q<3;q++){
        cpx n0 = cadd(cmul(r0, T[bs[q]][0][0]), cmul(r1, T[bs[q]][1][0]));
        cpx n1 = cadd(cmul(r0, T[bs[q]][0][1]), cmul(r1, T[bs[q]][1][1]));
        r0 = n0; r1 = n1;
      }
      u4[pat][0] = r0; u4[pat][1] = r1;
    } else if (kind == 1){
      int p3=pat>>3, p2=(pat>>2)&1, p1=(pat>>1)&1, p0=pat&1;
      cpx M00=T[p3][0][0], M01=T[p3][0][1], M10=T[p3][1][0], M11=T[p3][1][1];
      int bs[3] = {p2, p1, p0};
      for (int q=0;q<3;q++){
        const cpx (*Tb)[2] = T[bs[q]];
        cpx N00 = cadd(cmul(M00,Tb[0][0]), cmul(M01,Tb[1][0]));
        cpx N01 = cadd(cmul(M00,Tb[0][1]), cmul(M01,Tb[1][1]));
        cpx N10 = cadd(cmul(M10,Tb[0][0]), cmul(M11,Tb[1][0]));
        cpx N11 = cadd(cmul(M10,Tb[0][1]), cmul(M11,Tb[1][1]));
        M00=N00; M01=N01; M10=N10; M11=N11;
      }
      M4[pat][0]=M00; M4[pat][1]=M01; M4[pat][2]=M10; M4[pat][3]=M11;
    } else {
      int b3=pat>>3, b2=(pat>>2)&1, b1=(pat>>1)&1, b0=pat&1;
      // e(b1,b0)_y = Uent((b1<<1)|b0, y<<1)
      int row = (b1<<1)|b0;
      cpx v0 = czero(), v1 = czero();
      for (int k=0;k<4;k++){
        v0 = cadd(v0, cmul(R[1][row*4+k], R[0][k*4+0]));
        v1 = cadd(v1, cmul(R[1][row*4+k], R[0][k*4+2]));
      }
      // v = T^{b2} v; v = T^{b3} v
      cpx n0 = cadd(cmul(T[b2][0][0],v0), cmul(T[b2][0][1],v1));
      cpx n1 = cadd(cmul(T[b2][1][0],v0), cmul(T[b2][1][1],v1));
      v0=n0; v1=n1;
      n0 = cadd(cmul(T[b3][0][0],v0), cmul(T[b3][0][1],v1));
      n1 = cadd(cmul(T[b3][1][0],v0), cmul(T[b3][1][1],v1));
      f4[pat][0]=n0; f4[pat][1]=n1;
    }
  }
  __syncthreads();

  // ---- Phase 5: combine + coalesced store. i = (bid<<10)|(t<<2)|k ----
  unsigned bid = blockIdx.x;
  cpx r0 = u4[bid>>6][0], r1 = u4[bid>>6][1];
  {
    const cpx* Ma = M4[(bid>>2)&15u];                 // bits 15..12
    cpx n0 = cadd(cmul(r0,Ma[0]), cmul(r1,Ma[2]));
    cpx n1 = cadd(cmul(r0,Ma[1]), cmul(r1,Ma[3]));
    r0=n0; r1=n1;
  }
  {
    const cpx* Mb = M4[((bid&3u)<<2)|((unsigned)(t>>6)&3u)];  // bits 11..8
    cpx n0 = cadd(cmul(r0,Mb[0]), cmul(r1,Mb[2]));
    cpx n1 = cadd(cmul(r0,Mb[1]), cmul(r1,Mb[3]));
    r0=n0; r1=n1;
  }
  {
    const cpx* Mc = M4[(t>>2)&15];                    // bits 7..4
    cpx n0 = cadd(cmul(r0,Mc[0]), cmul(r1,Mc[2]));
    cpx n1 = cadd(cmul(r0,Mc[1]), cmul(r1,Mc[3]));
    r0=n0; r1=n1;
  }
  int fb = (t&3)<<2;                                  // bits 3..2 from t, 1..0 = k
  float4 res; cpx y;
  y = cadd(cmul(r0, f4[fb  ][0]), cmul(r1, f4[fb  ][1])); res.x = y.x*y.x + y.y*y.y;
  y = cadd(cmul(r0, f4[fb|1][0]), cmul(r1, f4[fb|1][1])); res.y = y.x*y.x + y.y*y.y;
  y = cadd(cmul(r0, f4[fb|2][0]), cmul(r1, f4[fb|2][1])); res.z = y.x*y.x + y.y*y.y;
  y = cadd(cmul(r0, f4[fb|3][0]), cmul(r1, f4[fb|3][1])); res.w = y.x*y.x + y.y*y.y;
  ((float4*)out)[(bid<<8) | (unsigned)t] = res;
}

extern "C" void kernel_launch(void* const* d_in, const int* in_sizes, int n_in,
                              void* d_out, int out_size, void* d_ws, size_t ws_size,
                              hipStream_t stream) {
  const float* params = (const float*)d_in[0];
  mps_fused<<<1024, 256, 0, stream>>>(params, (float*)d_out);
}

// Round 6
// 21.085 us; speedup vs baseline: 2.0509x; 2.0509x over previous
//
#include <hip/hip_runtime.h>

typedef float2 cpx;

__device__ __forceinline__ cpx cmul(cpx a, cpx b){
  return make_float2(a.x*b.x - a.y*b.y, a.x*b.y + a.y*b.x);
}
__device__ __forceinline__ cpx cadd(cpx a, cpx b){ return make_float2(a.x+b.x, a.y+b.y); }
__device__ __forceinline__ cpx czero(){ return make_float2(0.f,0.f); }

// p: 1=X -> RY(-90)=[[C,C],[-C,C]], 2=Y -> RX(+90)=[[C,-iC],[-iC,C]], 3=Z -> I
__device__ __forceinline__ cpx basis_e(int p, int i, int j){
  const float C = 0.70710678f;
  if (p==1){ float s = (i==1 && j==0) ? -C : C; return make_float2(s, 0.f); }
  else if (p==2){ if (i==j) return make_float2(C,0.f); return make_float2(0.f,-C); }
  else { return make_float2(i==j ? 1.f : 0.f, 0.f); }
}

// 1=RX, 2=RY, 3=RZ (half-angle ch, sh)
__device__ __forceinline__ cpx rot_e(int p, int i, int j, float ch, float sh){
  if (p==1){ if (i==j) return make_float2(ch,0.f); return make_float2(0.f,-sh); }
  else if (p==2){ if (i==j) return make_float2(ch,0.f); return make_float2(i==1?sh:-sh, 0.f); }
  else { if (i!=j) return czero(); return make_float2(ch, i==0?-sh:sh); }
}

// Entry (r,c) of gate i (1..15), closed form. pa=i>>2, pb=i&3 (0=I,1=X,2=Y,3=Z).
__device__ __forceinline__ cpx gate_entry(int i, int r, int c, float ch, float sh){
  int pa = i>>2, pb = i&3;
  if (pa==0 || pb==0){
    int p = pa ? pa : pb;
    if (pa) return ((r&1)==(c&1))   ? rot_e(p, r>>1, c>>1, ch, sh) : czero();
    else    return ((r>>1)==(c>>1)) ? rot_e(p, r&1,  c&1,  ch, sh) : czero();
  } else {
    cpx em = make_float2(ch,-sh), ep = make_float2(ch,sh);
    cpx s = czero();
    #pragma unroll
    for (int m=0;m<4;m++){
      cpx Prm = cmul(basis_e(pa, r>>1, m>>1), basis_e(pb, r&1, m&1));
      cpx Pmc = cmul(basis_e(pa, m>>1, c>>1), basis_e(pb, m&1, c&1));
      cpx d = (m==0 || m==3) ? em : ep;
      s = cadd(s, cmul(cmul(Prm, d), Pmc));
    }
    return s;
  }
}

// Select 2x2 matrix T^bb into named regs (no runtime-indexed arrays -> stays in VGPRs)
#define SELT(bb, m00,m01,m10,m11) \
  m00 = (bb) ? t100 : t000; m01 = (bb) ? t101 : t001; \
  m10 = (bb) ? t110 : t010; m11 = (bb) ? t111 : t011;

// Single-wave workgroups (barriers ~free). Each block redundantly builds the
// tables in ~6 wave-synchronous phases, then writes its 256-float slice.
// MPS bond-2: psi(b19..b0) = s(b19)^T T^{b18}...T^{b2} e(b1,b0);
//   T[z][yi][yo] = U[(z<<1)|yo, yi<<1];  e(b1,b0)_y = T[b1][y][b0].
// out(i) = | u4[i>>16] * M4[(i>>12)&15] * M4[(i>>8)&15] * M4[(i>>4)&15] * f4[i&15] |^2
__global__ __launch_bounds__(64) void mps_fused(const float* __restrict__ params,
                                                float* __restrict__ out){
  __shared__ cpx Gm[16][16];   // gates 1..15
  __shared__ cpx P[8][16];     // pair products, P[7]=G15
  __shared__ cpx Q[4][16];     // U = Q3*Q2*Q1*Q0
  __shared__ cpx Tl[8];        // T[z][yi][yo] at (z<<2)|(yi<<1)|yo
  __shared__ cpx u4[16][2];
  __shared__ cpx M4p[16][5];   // padded stride 5 (40B) -> conflict-free rows
  __shared__ cpx f4p[16][3];   // padded stride 3 (24B)
  const int t = threadIdx.x;

  // ---- Phase A0: all 15 gate matrices (jobs j = gate*16 + entry) ----
  for (int j = t + 16; j < 256; j += 64){
    int i = j >> 4, e = j & 15;
    float h = 0.5f*params[i-1];
    Gm[i][e] = gate_entry(i, e>>2, e&3, cosf(h), sinf(h));
  }
  __syncthreads();

  // ---- Phase A1: P[p] = G_{2p+2}*G_{2p+1} (p<7), P[7]=G15 ----
  for (int j = t; j < 128; j += 64){
    int p = j>>4, e = j&15, r = e>>2, c = e&3;
    if (p < 7){
      cpx s = czero();
      #pragma unroll
      for (int k=0;k<4;k++) s = cadd(s, cmul(Gm[2*p+2][r*4+k], Gm[2*p+1][k*4+c]));
      P[p][e] = s;
    } else {
      P[7][e] = Gm[15][e];
    }
  }
  __syncthreads();

  // ---- Phase B: Q[p] = P[2p+1]*P[2p] ----
  {
    int p = t>>4, e = t&15, r = e>>2, c = e&3;
    cpx s = czero();
    #pragma unroll
    for (int k=0;k<4;k++) s = cadd(s, cmul(P[2*p+1][r*4+k], P[2*p][k*4+c]));
    Q[p][e] = s;
  }
  __syncthreads();

  // ---- Phase C: the 8 needed U entries: T[z][yi][yo] = U[(z<<1)|yo, yi<<1] ----
  if (t < 8){
    int z=(t>>2)&1, yi=(t>>1)&1, yo=t&1;
    int a=(z<<1)|yo, b=yi<<1;
    cpx r0=Q[3][a*4+0], r1=Q[3][a*4+1], r2=Q[3][a*4+2], r3=Q[3][a*4+3];
    cpx n0,n1,n2,n3;
    // r <- r * Q2
    n0 = cadd(cadd(cmul(r0,Q[2][0]), cmul(r1,Q[2][4])), cadd(cmul(r2,Q[2][8]),  cmul(r3,Q[2][12])));
    n1 = cadd(cadd(cmul(r0,Q[2][1]), cmul(r1,Q[2][5])), cadd(cmul(r2,Q[2][9]),  cmul(r3,Q[2][13])));
    n2 = cadd(cadd(cmul(r0,Q[2][2]), cmul(r1,Q[2][6])), cadd(cmul(r2,Q[2][10]), cmul(r3,Q[2][14])));
    n3 = cadd(cadd(cmul(r0,Q[2][3]), cmul(r1,Q[2][7])), cadd(cmul(r2,Q[2][11]), cmul(r3,Q[2][15])));
    r0=n0; r1=n1; r2=n2; r3=n3;
    // r <- r * Q1
    n0 = cadd(cadd(cmul(r0,Q[1][0]), cmul(r1,Q[1][4])), cadd(cmul(r2,Q[1][8]),  cmul(r3,Q[1][12])));
    n1 = cadd(cadd(cmul(r0,Q[1][1]), cmul(r1,Q[1][5])), cadd(cmul(r2,Q[1][9]),  cmul(r3,Q[1][13])));
    n2 = cadd(cadd(cmul(r0,Q[1][2]), cmul(r1,Q[1][6])), cadd(cmul(r2,Q[1][10]), cmul(r3,Q[1][14])));
    n3 = cadd(cadd(cmul(r0,Q[1][3]), cmul(r1,Q[1][7])), cadd(cmul(r2,Q[1][11]), cmul(r3,Q[1][15])));
    r0=n0; r1=n1; r2=n2; r3=n3;
    // entry = r . col b of Q0
    cpx s = cadd(cadd(cmul(r0,Q[0][b]), cmul(r1,Q[0][4+b])), cadd(cmul(r2,Q[0][8+b]), cmul(r3,Q[0][12+b])));
    Tl[t] = s;
  }
  __syncthreads();

  // ---- Phase D: tables from T (named regs + ternary selects only) ----
  if (t < 48){
    cpx t000=Tl[0], t001=Tl[1], t010=Tl[2], t011=Tl[3];
    cpx t100=Tl[4], t101=Tl[5], t110=Tl[6], t111=Tl[7];
    int kind = t>>4, pat = t&15;
    int q3=pat>>3, q2=(pat>>2)&1, q1=(pat>>1)&1, q0=pat&1;
    cpx m00,m01,m10,m11;
    if (kind == 0){
      // u4: s(q3)=row0 of T^{q3}, then x T^{q2}, T^{q1}, T^{q0}
      cpx r0 = q3 ? t100 : t000;
      cpx r1 = q3 ? t101 : t001;
      SELT(q2, m00,m01,m10,m11);
      { cpx n0 = cadd(cmul(r0,m00),cmul(r1,m10)); cpx n1 = cadd(cmul(r0,m01),cmul(r1,m11)); r0=n0; r1=n1; }
      SELT(q1, m00,m01,m10,m11);
      { cpx n0 = cadd(cmul(r0,m00),cmul(r1,m10)); cpx n1 = cadd(cmul(r0,m01),cmul(r1,m11)); r0=n0; r1=n1; }
      SELT(q0, m00,m01,m10,m11);
      { cpx n0 = cadd(cmul(r0,m00),cmul(r1,m10)); cpx n1 = cadd(cmul(r0,m01),cmul(r1,m11)); r0=n0; r1=n1; }
      u4[pat][0]=r0; u4[pat][1]=r1;
    } else if (kind == 1){
      // M4 = T^{q3} T^{q2} T^{q1} T^{q0}
      cpx M00,M01,M10,M11;
      SELT(q3, M00,M01,M10,M11);
      SELT(q2, m00,m01,m10,m11);
      { cpx N00=cadd(cmul(M00,m00),cmul(M01,m10)), N01=cadd(cmul(M00,m01),cmul(M01,m11));
        cpx N10=cadd(cmul(M10,m00),cmul(M11,m10)), N11=cadd(cmul(M10,m01),cmul(M11,m11));
        M00=N00; M01=N01; M10=N10; M11=N11; }
      SELT(q1, m00,m01,m10,m11);
      { cpx N00=cadd(cmul(M00,m00),cmul(M01,m10)), N01=cadd(cmul(M00,m01),cmul(M01,m11));
        cpx N10=cadd(cmul(M10,m00),cmul(M11,m10)), N11=cadd(cmul(M10,m01),cmul(M11,m11));
        M00=N00; M01=N01; M10=N10; M11=N11; }
      SELT(q0, m00,m01,m10,m11);
      { cpx N00=cadd(cmul(M00,m00),cmul(M01,m10)), N01=cadd(cmul(M00,m01),cmul(M01,m11));
        cpx N10=cadd(cmul(M10,m00),cmul(M11,m10)), N11=cadd(cmul(M10,m01),cmul(M11,m11));
        M00=N00; M01=N01; M10=N10; M11=N11; }
      M4p[pat][0]=M00; M4p[pat][1]=M01; M4p[pat][2]=M10; M4p[pat][3]=M11;
    } else {
      // f4: seed e(b1,b0)_y = T[b1][y][b0] with b3=q3,b2=q2,b1=q1,b0=q0; then T^{b2}, T^{b3} (col-vec)
      cpx v0 = q1 ? (q0 ? t101 : t100) : (q0 ? t001 : t000);
      cpx v1 = q1 ? (q0 ? t111 : t110) : (q0 ? t011 : t010);
      SELT(q2, m00,m01,m10,m11);
      { cpx n0 = cadd(cmul(m00,v0),cmul(m01,v1)); cpx n1 = cadd(cmul(m10,v0),cmul(m11,v1)); v0=n0; v1=n1; }
      SELT(q3, m00,m01,m10,m11);
      { cpx n0 = cadd(cmul(m00,v0),cmul(m01,v1)); cpx n1 = cadd(cmul(m10,v0),cmul(m11,v1)); v0=n0; v1=n1; }
      f4p[pat][0]=v0; f4p[pat][1]=v1;
    }
  }
  __syncthreads();

  // ---- Phase E: combine + coalesced store. i = (bid<<8)|(t<<2)|k ----
  unsigned bid = blockIdx.x;
  cpx r0 = u4[bid>>8][0], r1 = u4[bid>>8][1];
  {
    const cpx* Ma = M4p[(bid>>4)&15u];               // bits 15..12 (block-uniform)
    cpx n0 = cadd(cmul(r0,Ma[0]), cmul(r1,Ma[2]));
    cpx n1 = cadd(cmul(r0,Ma[1]), cmul(r1,Ma[3]));
    r0=n0; r1=n1;
  }
  {
    const cpx* Mb = M4p[bid&15u];                    // bits 11..8 (block-uniform)
    cpx n0 = cadd(cmul(r0,Mb[0]), cmul(r1,Mb[2]));
    cpx n1 = cadd(cmul(r0,Mb[1]), cmul(r1,Mb[3]));
    r0=n0; r1=n1;
  }
  {
    const cpx* Mc = M4p[(t>>2)&15];                  // bits 7..4 (per-thread)
    cpx n0 = cadd(cmul(r0,Mc[0]), cmul(r1,Mc[2]));
    cpx n1 = cadd(cmul(r0,Mc[1]), cmul(r1,Mc[3]));
    r0=n0; r1=n1;
  }
  int fb = (t&3)<<2;                                 // bits 3..2 from t, 1..0 = k
  float4 res; cpx y;
  y = cadd(cmul(r0, f4p[fb  ][0]), cmul(r1, f4p[fb  ][1])); res.x = y.x*y.x + y.y*y.y;
  y = cadd(cmul(r0, f4p[fb|1][0]), cmul(r1, f4p[fb|1][1])); res.y = y.x*y.x + y.y*y.y;
  y = cadd(cmul(r0, f4p[fb|2][0]), cmul(r1, f4p[fb|2][1])); res.z = y.x*y.x + y.y*y.y;
  y = cadd(cmul(r0, f4p[fb|3][0]), cmul(r1, f4p[fb|3][1])); res.w = y.x*y.x + y.y*y.y;
  ((float4*)out)[(bid<<6) | (unsigned)t] = res;
}

extern "C" void kernel_launch(void* const* d_in, const int* in_sizes, int n_in,
                              void* d_out, int out_size, void* d_ws, size_t ws_size,
                              hipStream_t stream) {
  const float* params = (const float*)d_in[0];
  mps_fused<<<4096, 64, 0, stream>>>(params, (float*)d_out);
}

// Round 7
// 11.574 us; speedup vs baseline: 3.7360x; 1.8217x over previous
//
#include <hip/hip_runtime.h>

typedef float2 cpx;

__device__ __forceinline__ cpx cmul(cpx a, cpx b){
  return make_float2(a.x*b.x - a.y*b.y, a.x*b.y + a.y*b.x);
}
__device__ __forceinline__ cpx cadd(cpx a, cpx b){ return make_float2(a.x+b.x, a.y+b.y); }
__device__ __forceinline__ cpx czero(){ return make_float2(0.f,0.f); }

// p: 1=X -> RY(-90)=[[C,C],[-C,C]], 2=Y -> RX(+90)=[[C,-iC],[-iC,C]], 3=Z -> I
__device__ __forceinline__ cpx basis_e(int p, int i, int j){
  const float C = 0.70710678f;
  if (p==1){ float s = (i==1 && j==0) ? -C : C; return make_float2(s, 0.f); }
  else if (p==2){ if (i==j) return make_float2(C,0.f); return make_float2(0.f,-C); }
  else { return make_float2(i==j ? 1.f : 0.f, 0.f); }
}

// 1=RX, 2=RY, 3=RZ (half-angle ch, sh)
__device__ __forceinline__ cpx rot_e(int p, int i, int j, float ch, float sh){
  if (p==1){ if (i==j) return make_float2(ch,0.f); return make_float2(0.f,-sh); }
  else if (p==2){ if (i==j) return make_float2(ch,0.f); return make_float2(i==1?sh:-sh, 0.f); }
  else { if (i!=j) return czero(); return make_float2(ch, i==0?-sh:sh); }
}

// Entry (r,c) of gate i (1..15), closed form. pa=i>>2, pb=i&3 (0=I,1=X,2=Y,3=Z).
__device__ __forceinline__ cpx gate_entry(int i, int r, int c, float ch, float sh){
  int pa = i>>2, pb = i&3;
  if (pa==0 || pb==0){
    int p = pa ? pa : pb;
    if (pa) return ((r&1)==(c&1))   ? rot_e(p, r>>1, c>>1, ch, sh) : czero();
    else    return ((r>>1)==(c>>1)) ? rot_e(p, r&1,  c&1,  ch, sh) : czero();
  } else {
    cpx em = make_float2(ch,-sh), ep = make_float2(ch,sh);
    cpx s = czero();
    #pragma unroll
    for (int m=0;m<4;m++){
      cpx Prm = cmul(basis_e(pa, r>>1, m>>1), basis_e(pb, r&1, m&1));
      cpx Pmc = cmul(basis_e(pa, m>>1, c>>1), basis_e(pb, m&1, c&1));
      cpx d = (m==0 || m==3) ? em : ep;
      s = cadd(s, cmul(cmul(Prm, d), Pmc));
    }
    return s;
  }
}

// Select 2x2 matrix T^bb into named regs (no runtime-indexed arrays -> stays in VGPRs)
#define SELT(bb, m00,m01,m10,m11) \
  m00 = (bb) ? t100 : t000; m01 = (bb) ? t101 : t001; \
  m10 = (bb) ? t110 : t010; m11 = (bb) ? t111 : t011;

// MPS bond-2: psi(b19..b0) = s(b19)^T T^{b18}...T^{b2} e(b1,b0);
//   T[z][yi][yo] = U[(z<<1)|yo, yi<<1];  e(b1,b0)_y = T[b1][y][b0].
// out(i) = | u4[i>>16] * M4[(i>>12)&15] * M4[(i>>8)&15] * M4[(i>>4)&15] * f4[i&15] |^2
// 6 wide phases (5 barriers), every thread does at most ONE fast-trig gate entry.
__global__ __launch_bounds__(256) void mps_fused(const float* __restrict__ params,
                                                 float* __restrict__ out){
  __shared__ cpx Gm[16][16];   // gates 1..15
  __shared__ cpx P[8][16];     // pair products, P[7]=G15
  __shared__ cpx Q[4][16];     // U = Q3*Q2*Q1*Q0
  __shared__ cpx Tl[8];        // T[z][yi][yo] at (z<<2)|(yi<<1)|yo
  __shared__ cpx u4[16][2];
  __shared__ cpx M4p[16][5];   // padded stride 5 -> conflict-free rows
  __shared__ cpx f4p[16][3];   // padded stride 3
  const int t = threadIdx.x;

  // ---- Phase A: all 240 gate entries in parallel, HW trig (v_sin/v_cos) ----
  if (t >= 16){
    int i = t>>4, e = t&15;
    float h = 0.5f*params[i-1];
    Gm[i][e] = gate_entry(i, e>>2, e&3, __cosf(h), __sinf(h));
  }
  __syncthreads();

  // ---- Phase B: P[p] = G_{2p+2}*G_{2p+1} (p<7), P[7]=G15 ----
  if (t < 128){
    int p = t>>4, e = t&15, r = e>>2, c = e&3;
    if (p < 7){
      cpx s = czero();
      #pragma unroll
      for (int k=0;k<4;k++) s = cadd(s, cmul(Gm[2*p+2][r*4+k], Gm[2*p+1][k*4+c]));
      P[p][e] = s;
    } else {
      P[7][e] = Gm[15][e];
    }
  }
  __syncthreads();

  // ---- Phase C: Q[p] = P[2p+1]*P[2p] ----
  if (t < 64){
    int p = t>>4, e = t&15, r = e>>2, c = e&3;
    cpx s = czero();
    #pragma unroll
    for (int k=0;k<4;k++) s = cadd(s, cmul(P[2*p+1][r*4+k], P[2*p][k*4+c]));
    Q[p][e] = s;
  }
  __syncthreads();

  // ---- Phase D: the 8 needed U entries: T[z][yi][yo] = U[(z<<1)|yo, yi<<1] ----
  if (t < 8){
    int z=(t>>2)&1, yi=(t>>1)&1, yo=t&1;
    int a=(z<<1)|yo, b=yi<<1;
    cpx r0=Q[3][a*4+0], r1=Q[3][a*4+1], r2=Q[3][a*4+2], r3=Q[3][a*4+3];
    cpx n0,n1,n2,n3;
    // r <- r * Q2
    n0 = cadd(cadd(cmul(r0,Q[2][0]), cmul(r1,Q[2][4])), cadd(cmul(r2,Q[2][8]),  cmul(r3,Q[2][12])));
    n1 = cadd(cadd(cmul(r0,Q[2][1]), cmul(r1,Q[2][5])), cadd(cmul(r2,Q[2][9]),  cmul(r3,Q[2][13])));
    n2 = cadd(cadd(cmul(r0,Q[2][2]), cmul(r1,Q[2][6])), cadd(cmul(r2,Q[2][10]), cmul(r3,Q[2][14])));
    n3 = cadd(cadd(cmul(r0,Q[2][3]), cmul(r1,Q[2][7])), cadd(cmul(r2,Q[2][11]), cmul(r3,Q[2][15])));
    r0=n0; r1=n1; r2=n2; r3=n3;
    // r <- r * Q1
    n0 = cadd(cadd(cmul(r0,Q[1][0]), cmul(r1,Q[1][4])), cadd(cmul(r2,Q[1][8]),  cmul(r3,Q[1][12])));
    n1 = cadd(cadd(cmul(r0,Q[1][1]), cmul(r1,Q[1][5])), cadd(cmul(r2,Q[1][9]),  cmul(r3,Q[1][13])));
    n2 = cadd(cadd(cmul(r0,Q[1][2]), cmul(r1,Q[1][6])), cadd(cmul(r2,Q[1][10]), cmul(r3,Q[1][14])));
    n3 = cadd(cadd(cmul(r0,Q[1][3]), cmul(r1,Q[1][7])), cadd(cmul(r2,Q[1][11]), cmul(r3,Q[1][15])));
    r0=n0; r1=n1; r2=n2; r3=n3;
    // entry = r . col b of Q0
    cpx s = cadd(cadd(cmul(r0,Q[0][b]), cmul(r1,Q[0][4+b])), cadd(cmul(r2,Q[0][8+b]), cmul(r3,Q[0][12+b])));
    Tl[t] = s;
  }
  __syncthreads();

  // ---- Phase E: tables from T (named regs + ternary selects only) ----
  if (t < 48){
    cpx t000=Tl[0], t001=Tl[1], t010=Tl[2], t011=Tl[3];
    cpx t100=Tl[4], t101=Tl[5], t110=Tl[6], t111=Tl[7];
    int kind = t>>4, pat = t&15;
    int q3=pat>>3, q2=(pat>>2)&1, q1=(pat>>1)&1, q0=pat&1;
    cpx m00,m01,m10,m11;
    if (kind == 0){
      // u4: s(q3)=row0 of T^{q3}, then x T^{q2}, T^{q1}, T^{q0}
      cpx r0 = q3 ? t100 : t000;
      cpx r1 = q3 ? t101 : t001;
      SELT(q2, m00,m01,m10,m11);
      { cpx n0 = cadd(cmul(r0,m00),cmul(r1,m10)); cpx n1 = cadd(cmul(r0,m01),cmul(r1,m11)); r0=n0; r1=n1; }
      SELT(q1, m00,m01,m10,m11);
      { cpx n0 = cadd(cmul(r0,m00),cmul(r1,m10)); cpx n1 = cadd(cmul(r0,m01),cmul(r1,m11)); r0=n0; r1=n1; }
      SELT(q0, m00,m01,m10,m11);
      { cpx n0 = cadd(cmul(r0,m00),cmul(r1,m10)); cpx n1 = cadd(cmul(r0,m01),cmul(r1,m11)); r0=n0; r1=n1; }
      u4[pat][0]=r0; u4[pat][1]=r1;
    } else if (kind == 1){
      // M4 = T^{q3} T^{q2} T^{q1} T^{q0}
      cpx M00,M01,M10,M11;
      SELT(q3, M00,M01,M10,M11);
      SELT(q2, m00,m01,m10,m11);
      { cpx N00=cadd(cmul(M00,m00),cmul(M01,m10)), N01=cadd(cmul(M00,m01),cmul(M01,m11));
        cpx N10=cadd(cmul(M10,m00),cmul(M11,m10)), N11=cadd(cmul(M10,m01),cmul(M11,m11));
        M00=N00; M01=N01; M10=N10; M11=N11; }
      SELT(q1, m00,m01,m10,m11);
      { cpx N00=cadd(cmul(M00,m00),cmul(M01,m10)), N01=cadd(cmul(M00,m01),cmul(M01,m11));
        cpx N10=cadd(cmul(M10,m00),cmul(M11,m10)), N11=cadd(cmul(M10,m01),cmul(M11,m11));
        M00=N00; M01=N01; M10=N10; M11=N11; }
      SELT(q0, m00,m01,m10,m11);
      { cpx N00=cadd(cmul(M00,m00),cmul(M01,m10)), N01=cadd(cmul(M00,m01),cmul(M01,m11));
        cpx N10=cadd(cmul(M10,m00),cmul(M11,m10)), N11=cadd(cmul(M10,m01),cmul(M11,m11));
        M00=N00; M01=N01; M10=N10; M11=N11; }
      M4p[pat][0]=M00; M4p[pat][1]=M01; M4p[pat][2]=M10; M4p[pat][3]=M11;
    } else {
      // f4: seed e(b1,b0)_y = T[b1][y][b0]; then apply T^{b2}, T^{b3} (col-vec)
      cpx v0 = q1 ? (q0 ? t101 : t100) : (q0 ? t001 : t000);
      cpx v1 = q1 ? (q0 ? t111 : t110) : (q0 ? t011 : t010);
      SELT(q2, m00,m01,m10,m11);
      { cpx n0 = cadd(cmul(m00,v0),cmul(m01,v1)); cpx n1 = cadd(cmul(m10,v0),cmul(m11,v1)); v0=n0; v1=n1; }
      SELT(q3, m00,m01,m10,m11);
      { cpx n0 = cadd(cmul(m00,v0),cmul(m01,v1)); cpx n1 = cadd(cmul(m10,v0),cmul(m11,v1)); v0=n0; v1=n1; }
      f4p[pat][0]=v0; f4p[pat][1]=v1;
    }
  }
  __syncthreads();

  // ---- Phase F: combine + coalesced store. i = (bid<<10)|(t<<2)|k ----
  unsigned bid = blockIdx.x;
  cpx r0 = u4[bid>>6][0], r1 = u4[bid>>6][1];
  {
    const cpx* Ma = M4p[(bid>>2)&15u];               // bits 15..12 (block-uniform)
    cpx n0 = cadd(cmul(r0,Ma[0]), cmul(r1,Ma[2]));
    cpx n1 = cadd(cmul(r0,Ma[1]), cmul(r1,Ma[3]));
    r0=n0; r1=n1;
  }
  {
    const cpx* Mb = M4p[((bid&3u)<<2)|((unsigned)(t>>6)&3u)];  // bits 11..8 (wave-uniform)
    cpx n0 = cadd(cmul(r0,Mb[0]), cmul(r1,Mb[2]));
    cpx n1 = cadd(cmul(r0,Mb[1]), cmul(r1,Mb[3]));
    r0=n0; r1=n1;
  }
  {
    const cpx* Mc = M4p[(t>>2)&15];                  // bits 7..4 (per-thread)
    cpx n0 = cadd(cmul(r0,Mc[0]), cmul(r1,Mc[2]));
    cpx n1 = cadd(cmul(r0,Mc[1]), cmul(r1,Mc[3]));
    r0=n0; r1=n1;
  }
  int fb = (t&3)<<2;                                 // bits 3..2 from t, 1..0 = k
  float4 res; cpx y;
  y = cadd(cmul(r0, f4p[fb  ][0]), cmul(r1, f4p[fb  ][1])); res.x = y.x*y.x + y.y*y.y;
  y = cadd(cmul(r0, f4p[fb|1][0]), cmul(r1, f4p[fb|1][1])); res.y = y.x*y.x + y.y*y.y;
  y = cadd(cmul(r0, f4p[fb|2][0]), cmul(r1, f4p[fb|2][1])); res.z = y.x*y.x + y.y*y.y;
  y = cadd(cmul(r0, f4p[fb|3][0]), cmul(r1, f4p[fb|3][1])); res.w = y.x*y.x + y.y*y.y;
  ((float4*)out)[(bid<<8) | (unsigned)t] = res;
}

extern "C" void kernel_launch(void* const* d_in, const int* in_sizes, int n_in,
                              void* d_out, int out_size, void* d_ws, size_t ws_size,
                              hipStream_t stream) {
  const float* params = (const float*)d_in[0];
  mps_fused<<<1024, 256, 0, stream>>>(params, (float*)d_out);
}

// Round 8
// 10.083 us; speedup vs baseline: 4.2886x; 1.1479x over previous
//
#include <hip/hip_runtime.h>

typedef float2 cpx;

__device__ __forceinline__ cpx cmul(cpx a, cpx b){
  return make_float2(a.x*b.x - a.y*b.y, a.x*b.y + a.y*b.x);
}
__device__ __forceinline__ cpx cadd(cpx a, cpx b){ return make_float2(a.x+b.x, a.y+b.y); }
__device__ __forceinline__ cpx czero(){ return make_float2(0.f,0.f); }

// 1=RX, 2=RY, 3=RZ (half-angle ch, sh)
__device__ __forceinline__ cpx rot_e(int p, int i, int j, float ch, float sh){
  if (p==1){ if (i==j) return make_float2(ch,0.f); return make_float2(0.f,-sh); }
  else if (p==2){ if (i==j) return make_float2(ch,0.f); return make_float2(i==1?sh:-sh, 0.f); }
  else { if (i!=j) return czero(); return make_float2(ch, i==0?-sh:sh); }
}

// A_p = B_p^2 : p=3 -> I ; p=1 (X, RY(-90)) -> [[0,1],[-1,0]] ; p=2 (Y, RX(+90)) -> [[0,-i],[-i,0]]
__device__ __forceinline__ cpx Ae(int p, int i, int j){
  if (p==3) return make_float2(i==j?1.f:0.f, 0.f);
  if (i==j) return czero();
  if (p==1) return make_float2(i==0?1.f:-1.f, 0.f);
  return make_float2(0.f,-1.f);
}

// Entry (r,c) of gate i (1..15). pa=i>>2, pb=i&3 (0=I,1=X,2=Y,3=Z).
// Composite (both non-I): G = ch*(Apa⊗Apb) - i*sh*(Z⊗Z)   [B·Z·B = Z exactly;
// derived from the faithful P*diag*P construction via kron mixed-product].
__device__ __forceinline__ cpx gate_entry(int i, int r, int c, float ch, float sh){
  int pa = i>>2, pb = i&3;
  if (pa==0 || pb==0){
    int p = pa ? pa : pb;
    if (pa) return ((r&1)==(c&1))   ? rot_e(p, r>>1, c>>1, ch, sh) : czero();
    else    return ((r>>1)==(c>>1)) ? rot_e(p, r&1,  c&1,  ch, sh) : czero();
  }
  cpx a = cmul(Ae(pa, r>>1, c>>1), Ae(pb, r&1, c&1));
  cpx g = make_float2(ch*a.x, ch*a.y);
  if (r==c){ float zz = (r==0 || r==3) ? 1.f : -1.f; g.y -= sh*zz; }
  return g;
}

// In-wave LDS sync: DS ops are FIFO per wave; drain lgkmcnt + block compiler motion.
#define WSYNC() do { __builtin_amdgcn_wave_barrier(); \
  asm volatile("s_waitcnt lgkmcnt(0)" ::: "memory"); \
  __builtin_amdgcn_wave_barrier(); } while(0)

// Select 2x2 matrix T^bb into named regs (no runtime-indexed arrays -> stays in VGPRs)
#define SELT(bb, m00,m01,m10,m11) \
  m00 = (bb) ? t100 : t000; m01 = (bb) ? t101 : t001; \
  m10 = (bb) ? t110 : t010; m11 = (bb) ? t111 : t011;

// MPS bond-2: psi(b19..b0) = s(b19)^T T^{b18}...T^{b2} e(b1,b0);
//   T[z][yi][yo] = U[(z<<1)|yo, yi<<1];  e(b1,b0)_y = T[b1][y][b0].
// out(i) = | u4[i>>16] * M4[(i>>12)&15] * M4[(i>>8)&15] * M4[(i>>4)&15] * f4[i&15] |^2
// Structure: A (wide, 1 barrier) -> wave-0 straight-line B,C,R,T,E (WSYNC only)
//            -> 1 barrier -> F (wide combine+store).
__global__ __launch_bounds__(256) void mps_fused(const float* __restrict__ params,
                                                 float* __restrict__ out){
  __shared__ cpx Gm[16][16];   // gates 1..15
  __shared__ cpx P[8][16];     // pair products, P[7]=G15
  __shared__ cpx Q[4][16];     // U = Q3*Q2*Q1*Q0
  __shared__ cpx R[2][16];     // R1=Q3*Q2, R0=Q1*Q0
  __shared__ cpx Tl[8];        // T[z][yi][yo] at (z<<2)|(yi<<1)|yo
  __shared__ cpx u4[16][2];
  __shared__ cpx M4p[16][5];   // padded stride 5 -> conflict-free rows
  __shared__ cpx f4p[16][3];   // padded stride 3
  const int t = threadIdx.x;

  // ---- Phase A: all 240 gate entries in parallel (closed-form, HW trig) ----
  if (t >= 16){
    int i = t>>4, e = t&15;
    float h = 0.5f*params[i-1];
    Gm[i][e] = gate_entry(i, e>>2, e&3, __cosf(h), __sinf(h));
  }
  __syncthreads();

  // ---- Wave-0 straight-line mid-section ----
  if (t < 64){
    // B: P[p] = G_{2p+2}*G_{2p+1} (p<7), P[7]=G15 ; jobs j=t, t+64
    #pragma unroll
    for (int jj=0; jj<2; ++jj){
      int j = t + jj*64;
      int p = j>>4, e = j&15, r = e>>2, c = e&3;
      if (p < 7){
        cpx s = czero();
        #pragma unroll
        for (int k=0;k<4;k++) s = cadd(s, cmul(Gm[2*p+2][r*4+k], Gm[2*p+1][k*4+c]));
        P[p][e] = s;
      } else {
        P[7][e] = Gm[15][e];
      }
    }
    WSYNC();

    // C: Q[p] = P[2p+1]*P[2p]
    {
      int p = t>>4, e = t&15, r = e>>2, c = e&3;
      cpx s = czero();
      #pragma unroll
      for (int k=0;k<4;k++) s = cadd(s, cmul(P[2*p+1][r*4+k], P[2*p][k*4+c]));
      Q[p][e] = s;
    }
    WSYNC();

    // R: R[p] = Q[2p+1]*Q[2p]  (R1*R0 = U)
    if (t < 32){
      int p = t>>4, e = t&15, r = e>>2, c = e&3;
      cpx s = czero();
      #pragma unroll
      for (int k=0;k<4;k++) s = cadd(s, cmul(Q[2*p+1][r*4+k], Q[2*p][k*4+c]));
      R[p][e] = s;
    }
    WSYNC();

    // T: the 8 needed U entries: T[z][yi][yo] = U[(z<<1)|yo, yi<<1] = row(R1) . col(R0)
    if (t < 8){
      int z=(t>>2)&1, yi=(t>>1)&1, yo=t&1;
      int a=(z<<1)|yo, b=yi<<1;
      cpx s = czero();
      #pragma unroll
      for (int k=0;k<4;k++) s = cadd(s, cmul(R[1][a*4+k], R[0][k*4+b]));
      Tl[t] = s;
    }
    WSYNC();

    // E: tables from T (named regs + ternary selects only)
    if (t < 48){
      cpx t000=Tl[0], t001=Tl[1], t010=Tl[2], t011=Tl[3];
      cpx t100=Tl[4], t101=Tl[5], t110=Tl[6], t111=Tl[7];
      int kind = t>>4, pat = t&15;
      int q3=pat>>3, q2=(pat>>2)&1, q1=(pat>>1)&1, q0=pat&1;
      cpx m00,m01,m10,m11;
      if (kind == 0){
        // u4: s(q3)=row0 of T^{q3}, then x T^{q2}, T^{q1}, T^{q0}
        cpx r0 = q3 ? t100 : t000;
        cpx r1 = q3 ? t101 : t001;
        SELT(q2, m00,m01,m10,m11);
        { cpx n0 = cadd(cmul(r0,m00),cmul(r1,m10)); cpx n1 = cadd(cmul(r0,m01),cmul(r1,m11)); r0=n0; r1=n1; }
        SELT(q1, m00,m01,m10,m11);
        { cpx n0 = cadd(cmul(r0,m00),cmul(r1,m10)); cpx n1 = cadd(cmul(r0,m01),cmul(r1,m11)); r0=n0; r1=n1; }
        SELT(q0, m00,m01,m10,m11);
        { cpx n0 = cadd(cmul(r0,m00),cmul(r1,m10)); cpx n1 = cadd(cmul(r0,m01),cmul(r1,m11)); r0=n0; r1=n1; }
        u4[pat][0]=r0; u4[pat][1]=r1;
      } else if (kind == 1){
        // M4 = T^{q3} T^{q2} T^{q1} T^{q0}
        cpx M00,M01,M10,M11;
        SELT(q3, M00,M01,M10,M11);
        SELT(q2, m00,m01,m10,m11);
        { cpx N00=cadd(cmul(M00,m00),cmul(M01,m10)), N01=cadd(cmul(M00,m01),cmul(M01,m11));
          cpx N10=cadd(cmul(M10,m00),cmul(M11,m10)), N11=cadd(cmul(M10,m01),cmul(M11,m11));
          M00=N00; M01=N01; M10=N10; M11=N11; }
        SELT(q1, m00,m01,m10,m11);
        { cpx N00=cadd(cmul(M00,m00),cmul(M01,m10)), N01=cadd(cmul(M00,m01),cmul(M01,m11));
          cpx N10=cadd(cmul(M10,m00),cmul(M11,m10)), N11=cadd(cmul(M10,m01),cmul(M11,m11));
          M00=N00; M01=N01; M10=N10; M11=N11; }
        SELT(q0, m00,m01,m10,m11);
        { cpx N00=cadd(cmul(M00,m00),cmul(M01,m10)), N01=cadd(cmul(M00,m01),cmul(M01,m11));
          cpx N10=cadd(cmul(M10,m00),cmul(M11,m10)), N11=cadd(cmul(M10,m01),cmul(M11,m11));
          M00=N00; M01=N01; M10=N10; M11=N11; }
        M4p[pat][0]=M00; M4p[pat][1]=M01; M4p[pat][2]=M10; M4p[pat][3]=M11;
      } else {
        // f4: seed e(b1,b0)_y = T[b1][y][b0]; then apply T^{b2}, T^{b3} (col-vec)
        cpx v0 = q1 ? (q0 ? t101 : t100) : (q0 ? t001 : t000);
        cpx v1 = q1 ? (q0 ? t111 : t110) : (q0 ? t011 : t010);
        SELT(q2, m00,m01,m10,m11);
        { cpx n0 = cadd(cmul(m00,v0),cmul(m01,v1)); cpx n1 = cadd(cmul(m10,v0),cmul(m11,v1)); v0=n0; v1=n1; }
        SELT(q3, m00,m01,m10,m11);
        { cpx n0 = cadd(cmul(m00,v0),cmul(m01,v1)); cpx n1 = cadd(cmul(m10,v0),cmul(m11,v1)); v0=n0; v1=n1; }
        f4p[pat][0]=v0; f4p[pat][1]=v1;
      }
    }
  }
  __syncthreads();

  // ---- Phase F: combine + coalesced store. i = (bid<<10)|(t<<2)|k ----
  unsigned bid = blockIdx.x;
  cpx r0 = u4[bid>>6][0], r1 = u4[bid>>6][1];
  {
    const cpx* Ma = M4p[(bid>>2)&15u];               // bits 15..12 (block-uniform)
    cpx n0 = cadd(cmul(r0,Ma[0]), cmul(r1,Ma[2]));
    cpx n1 = cadd(cmul(r0,Ma[1]), cmul(r1,Ma[3]));
    r0=n0; r1=n1;
  }
  {
    const cpx* Mb = M4p[((bid&3u)<<2)|((unsigned)(t>>6)&3u)];  // bits 11..8 (wave-uniform)
    cpx n0 = cadd(cmul(r0,Mb[0]), cmul(r1,Mb[2]));
    cpx n1 = cadd(cmul(r0,Mb[1]), cmul(r1,Mb[3]));
    r0=n0; r1=n1;
  }
  {
    const cpx* Mc = M4p[(t>>2)&15];                  // bits 7..4 (per-thread)
    cpx n0 = cadd(cmul(r0,Mc[0]), cmul(r1,Mc[2]));
    cpx n1 = cadd(cmul(r0,Mc[1]), cmul(r1,Mc[3]));
    r0=n0; r1=n1;
  }
  int fb = (t&3)<<2;                                 // bits 3..2 from t, 1..0 = k
  float4 res; cpx y;
  y = cadd(cmul(r0, f4p[fb  ][0]), cmul(r1, f4p[fb  ][1])); res.x = y.x*y.x + y.y*y.y;
  y = cadd(cmul(r0, f4p[fb|1][0]), cmul(r1, f4p[fb|1][1])); res.y = y.x*y.x + y.y*y.y;
  y = cadd(cmul(r0, f4p[fb|2][0]), cmul(r1, f4p[fb|2][1])); res.z = y.x*y.x + y.y*y.y;
  y = cadd(cmul(r0, f4p[fb|3][0]), cmul(r1, f4p[fb|3][1])); res.w = y.x*y.x + y.y*y.y;
  ((float4*)out)[(bid<<8) | (unsigned)t] = res;
}

extern "C" void kernel_launch(void* const* d_in, const int* in_sizes, int n_in,
                              void* d_out, int out_size, void* d_ws, size_t ws_size,
                              hipStream_t stream) {
  const float* params = (const float*)d_in[0];
  mps_fused<<<1024, 256, 0, stream>>>(params, (float*)d_out);
}